// Round 1
// 123.863 us; speedup vs baseline: 1.1346x; 1.1346x over previous
//
#include <hip/hip_runtime.h>
#include <math.h>

// Problem constants (fixed by reference)
#define B_ 8
#define N_ 384
#define D_ 256
#define H_ 1024

typedef __bf16 bh;
typedef __bf16 bf16x8 __attribute__((ext_vector_type(8)));
typedef __bf16 bf16x4 __attribute__((ext_vector_type(4)));
typedef float  f32x4  __attribute__((ext_vector_type(4)));
typedef _Float16 h2 __attribute__((ext_vector_type(2)));

#define LDB 72   // LDS row stride in bf16 for 64-wide K tiles: 144 B rows -> <=2-way banks on frag reads

#if __has_builtin(__builtin_amdgcn_fdot2)
#define FDOT2(a,b,c) __builtin_amdgcn_fdot2((a),(b),(c),false)
#else
#define FDOT2(a,b,c) ((c) + (float)(a).x*(float)(b).x + (float)(a).y*(float)(b).y)
#endif

__device__ inline h2 habs2(h2 x) {
    unsigned u = __builtin_bit_cast(unsigned, x) & 0x7fff7fffu;
    return __builtin_bit_cast(h2, u);
}

// split fp32 -> hi + lo bf16 (3xbf16 trick: a*b ~= ah*bh + ah*bl + al*bh, rel err ~2^-16)
__device__ inline void split2(float v, bh& h, bh& l) {
    h = (bh)v;
    l = (bh)(v - (float)h);
}

// box_num is logically int64; harness may hand int32. box_num >= 1 always, so
// int64-LE layout has all odd words zero -> runtime-detectable.
__device__ inline int load_boxnum(const int* __restrict__ p, int b) {
    bool is64 = ((p[1] | p[3] | p[5] | p[7]) == 0);
    return is64 ? p[2 * b] : p[b];
}

// ---------------- split3: fp32 -> (hi,lo) bf16 for up to 3 sources in ONE launch ----------------
// Hoists all in-GEMM split2 work out of the hot loops (W1 was re-split 48x, W2 8x).
__global__ __launch_bounds__(256) void split3_kernel(
        const float* __restrict__ s0, bh* __restrict__ h0, bh* __restrict__ l0, int n0,
        const float* __restrict__ s1, bh* __restrict__ h1, bh* __restrict__ l1, int n1,
        const float* __restrict__ s2, bh* __restrict__ h2_, bh* __restrict__ l2, int n2)
{
    const int total = n0 + n1 + n2;   // in float4 quads
    for (int qd = blockIdx.x * blockDim.x + threadIdx.x; qd < total; qd += gridDim.x * blockDim.x) {
        const float* s; bh* ph; bh* pl; int i;
        if (qd < n0)           { s = s0; ph = h0;  pl = l0; i = qd; }
        else if (qd < n0 + n1) { s = s1; ph = h1;  pl = l1; i = qd - n0; }
        else                   { s = s2; ph = h2_; pl = l2; i = qd - n0 - n1; }
        float4 v = *(const float4*)(s + 4 * (size_t)i);
        bf16x4 hv, lv; bh hh, ll;
        split2(v.x, hh, ll); hv[0] = hh; lv[0] = ll;
        split2(v.y, hh, ll); hv[1] = hh; lv[1] = ll;
        split2(v.z, hh, ll); hv[2] = hh; lv[2] = ll;
        split2(v.w, hh, ll); hv[3] = hh; lv[3] = ll;
        *(bf16x4*)(ph + 4 * (size_t)i) = hv;
        *(bf16x4*)(pl + 4 * (size_t)i) = lv;
    }
}

// ---------------- GEMM1: c1 = relu(x @ fc1_w^T + fc1_b), pre-split operands, K-stage=64 ----------------
__global__ __launch_bounds__(256) void gemm1_kernel(
        const bh* __restrict__ Ah_, const bh* __restrict__ Al_,   // (rows,256) pre-split x
        const bh* __restrict__ Wh_, const bh* __restrict__ Wl_,   // (1024,256) pre-split fc1_w
        const float* __restrict__ bias,
        bh* __restrict__ Ch, bh* __restrict__ Cl)                 // (rows,1024)
{
    __shared__ __align__(16) bh AhS[64 * LDB], AlS[64 * LDB], WhS[64 * LDB], WlS[64 * LDB];  // 36 KB
    const int tid = threadIdx.x;
    const int m0 = blockIdx.y * 64, n0 = blockIdx.x * 64;
    const int r = tid >> 2, kq = (tid & 3) * 16;   // staging: 4 threads/row x 16 elems
    const int lane = tid & 63, wv_ = tid >> 6;
    const int wm = (wv_ & 1) * 32, wn = (wv_ >> 1) * 32;
    const int l15 = lane & 15, q = lane >> 4;

    f32x4 acc[2][2] = {};
    for (int k0 = 0; k0 < D_; k0 += 64) {
        const bh* pah = Ah_ + (size_t)(m0 + r) * D_ + k0 + kq;
        const bh* pal = Al_ + (size_t)(m0 + r) * D_ + k0 + kq;
        const bh* pwh = Wh_ + (size_t)(n0 + r) * D_ + k0 + kq;
        const bh* pwl = Wl_ + (size_t)(n0 + r) * D_ + k0 + kq;
        bf16x8 ah0 = *(const bf16x8*)pah, ah1 = *(const bf16x8*)(pah + 8);
        bf16x8 al0 = *(const bf16x8*)pal, al1 = *(const bf16x8*)(pal + 8);
        bf16x8 wh0 = *(const bf16x8*)pwh, wh1 = *(const bf16x8*)(pwh + 8);
        bf16x8 wl0 = *(const bf16x8*)pwl, wl1 = *(const bf16x8*)(pwl + 8);
        __syncthreads();
        *(bf16x8*)&AhS[r * LDB + kq] = ah0;  *(bf16x8*)&AhS[r * LDB + kq + 8] = ah1;
        *(bf16x8*)&AlS[r * LDB + kq] = al0;  *(bf16x8*)&AlS[r * LDB + kq + 8] = al1;
        *(bf16x8*)&WhS[r * LDB + kq] = wh0;  *(bf16x8*)&WhS[r * LDB + kq + 8] = wh1;
        *(bf16x8*)&WlS[r * LDB + kq] = wl0;  *(bf16x8*)&WlS[r * LDB + kq + 8] = wl1;
        __syncthreads();
        #pragma unroll
        for (int ks = 0; ks < 2; ks++) {
            const int kb = ks * 32 + q * 8;
            bf16x8 fah[2], fal[2], fwh[2], fwl[2];
            #pragma unroll
            for (int mi = 0; mi < 2; mi++) {
                int row = wm + mi * 16 + l15;
                fah[mi] = *(const bf16x8*)&AhS[row * LDB + kb];
                fal[mi] = *(const bf16x8*)&AlS[row * LDB + kb];
            }
            #pragma unroll
            for (int ni = 0; ni < 2; ni++) {
                int row = wn + ni * 16 + l15;
                fwh[ni] = *(const bf16x8*)&WhS[row * LDB + kb];
                fwl[ni] = *(const bf16x8*)&WlS[row * LDB + kb];
            }
            #pragma unroll
            for (int mi = 0; mi < 2; mi++)
                #pragma unroll
                for (int ni = 0; ni < 2; ni++) {
                    acc[mi][ni] = __builtin_amdgcn_mfma_f32_16x16x32_bf16(fah[mi], fwh[ni], acc[mi][ni], 0, 0, 0);
                    acc[mi][ni] = __builtin_amdgcn_mfma_f32_16x16x32_bf16(fah[mi], fwl[ni], acc[mi][ni], 0, 0, 0);
                    acc[mi][ni] = __builtin_amdgcn_mfma_f32_16x16x32_bf16(fal[mi], fwh[ni], acc[mi][ni], 0, 0, 0);
                }
        }
    }
    #pragma unroll
    for (int ni = 0; ni < 2; ni++) {
        int col = n0 + wn + ni * 16 + l15;
        float bb = bias[col];
        #pragma unroll
        for (int mi = 0; mi < 2; mi++)
            #pragma unroll
            for (int reg = 0; reg < 4; reg++) {
                int row = m0 + wm + mi * 16 + q * 4 + reg;
                float v = fmaxf(acc[mi][ni][reg] + bb, 0.f);
                bh h, l; split2(v, h, l);
                size_t off = (size_t)row * H_ + col;
                Ch[off] = h; Cl[off] = l;
            }
    }
}

// ---------------- GEMM2: xhat = c1 @ fc2_w^T + fc2_b; fp32 + fp16 outputs; K-stage=64 ----------------
// 256 threads: 4 waves x (16 rows x 32 cols). grid (8,48)=384 blocks, 27.6 KB LDS.
__global__ __launch_bounds__(256) void gemm2_kernel(
        const bh* __restrict__ Ah_, const bh* __restrict__ Al_,   // (rows,1024) c1 hi/lo
        const bh* __restrict__ Wh_, const bh* __restrict__ Wl_,   // (256,1024) pre-split fc2_w
        const float* __restrict__ bias,
        float* __restrict__ C, _Float16* __restrict__ C16)        // (rows,256)
{
    __shared__ __align__(16) bh AhS[64 * LDB], AlS[64 * LDB], WhS[32 * LDB], WlS[32 * LDB];
    const int tid = threadIdx.x;
    const int m0 = blockIdx.y * 64, n0 = blockIdx.x * 32;
    const int lane = tid & 63, wv_ = tid >> 6;
    const int wm = wv_ * 16;
    const int l15 = lane & 15, q = lane >> 4;
    const int r = tid >> 2, kq = (tid & 3) * 16;    // A staging: 4 thr/row x 16 elems
    const int rw = tid >> 3, kw = (tid & 7) * 8;    // W staging: 8 thr/row x 8 elems

    f32x4 acc[2] = {};
    for (int k0 = 0; k0 < H_; k0 += 64) {
        const bh* pah = Ah_ + (size_t)(m0 + r) * H_ + k0 + kq;
        const bh* pal = Al_ + (size_t)(m0 + r) * H_ + k0 + kq;
        const bh* pwh = Wh_ + (size_t)(n0 + rw) * H_ + k0 + kw;
        const bh* pwl = Wl_ + (size_t)(n0 + rw) * H_ + k0 + kw;
        bf16x8 ah0 = *(const bf16x8*)pah, ah1 = *(const bf16x8*)(pah + 8);
        bf16x8 al0 = *(const bf16x8*)pal, al1 = *(const bf16x8*)(pal + 8);
        bf16x8 wh0 = *(const bf16x8*)pwh;
        bf16x8 wl0 = *(const bf16x8*)pwl;
        __syncthreads();
        *(bf16x8*)&AhS[r * LDB + kq] = ah0;  *(bf16x8*)&AhS[r * LDB + kq + 8] = ah1;
        *(bf16x8*)&AlS[r * LDB + kq] = al0;  *(bf16x8*)&AlS[r * LDB + kq + 8] = al1;
        *(bf16x8*)&WhS[rw * LDB + kw] = wh0;
        *(bf16x8*)&WlS[rw * LDB + kw] = wl0;
        __syncthreads();
        #pragma unroll
        for (int ks = 0; ks < 2; ks++) {
            const int kb = ks * 32 + q * 8;
            const int arow = wm + l15;
            bf16x8 fah = *(const bf16x8*)&AhS[arow * LDB + kb];
            bf16x8 fal = *(const bf16x8*)&AlS[arow * LDB + kb];
            #pragma unroll
            for (int ni = 0; ni < 2; ni++) {
                int row = ni * 16 + l15;
                bf16x8 fwh = *(const bf16x8*)&WhS[row * LDB + kb];
                bf16x8 fwl = *(const bf16x8*)&WlS[row * LDB + kb];
                acc[ni] = __builtin_amdgcn_mfma_f32_16x16x32_bf16(fah, fwh, acc[ni], 0, 0, 0);
                acc[ni] = __builtin_amdgcn_mfma_f32_16x16x32_bf16(fah, fwl, acc[ni], 0, 0, 0);
                acc[ni] = __builtin_amdgcn_mfma_f32_16x16x32_bf16(fal, fwh, acc[ni], 0, 0, 0);
            }
        }
    }
    #pragma unroll
    for (int ni = 0; ni < 2; ni++) {
        int col = n0 + ni * 16 + l15;
        float bb = bias[col];
        #pragma unroll
        for (int reg = 0; reg < 4; reg++) {
            int row = m0 + wm + q * 4 + reg;
            float v = acc[ni][reg] + bb;
            C[(size_t)row * D_ + col] = v;
            C16[(size_t)row * D_ + col] = (_Float16)v;   // bit-identical to dist's old in-kernel cvt
        }
    }
}

// ---------------- pairwise weighted L1 + mask + leaky ----------------
// Upper-triangle 64x64 tiles (21/batch, 168 blocks), mirror-written.
// 512 threads. Whole D=256 staged ONCE as fp16 into k2-major LDS -> single barrier,
// then 128 barrier-free packed-fp16 iterations at 2 waves/SIMD.
#define DLX 132   // row-slot stride (128 rows + 4 pad); 528 B per k2 -> 16B-aligned, reads <=2-way banks
__global__ __launch_bounds__(512) void dist_kernel(const _Float16* __restrict__ xh16,
                                                   const float* __restrict__ w,
                                                   const int* __restrict__ box_num,
                                                   float* __restrict__ dist) {
    __shared__ __align__(16) unsigned X[128 * DLX];   // [k2][row: 0-63 = i-block, 64-127 = j-block]
    __shared__ unsigned WkS[128];
    const int bidx = blockIdx.x;
    const int b = bidx / 21;
    int p = bidx % 21;
    int ti = 0;
    while (p >= 6 - ti) { p -= 6 - ti; ti++; }
    const int tj = ti + p;
    const int i0 = ti * 64, j0 = tj * 64;
    const int tid = threadIdx.x;
    const int lane = tid & 63;

    // sum(learn_w) per wave
    float sumw = w[lane] + w[lane + 64] + w[lane + 128] + w[lane + 192];
    #pragma unroll
    for (int off = 32; off > 0; off >>= 1) sumw += __shfl_xor(sumw, off);

    // w pairs as fp16x2 in LDS
    if (tid < 128) {
        float2 wp = *(const float2*)&w[2 * tid];
        h2 wv = {(_Float16)wp.x, (_Float16)wp.y};
        WkS[tid] = __builtin_bit_cast(unsigned, wv);
    }

    // stage 128 rows x 256 dims fp16 (64 KB) transposed to k2-major
    const int sr = tid >> 2, koff = (tid & 3) * 64;
    const int grow = (sr < 64) ? (i0 + sr) : (j0 + sr - 64);
    const _Float16* src = xh16 + ((size_t)b * N_ + grow) * D_ + koff;
    #pragma unroll
    for (int ld = 0; ld < 8; ld++) {
        uint4 v = *(const uint4*)(src + ld * 8);
        int k2 = (koff >> 1) + ld * 4;
        X[(k2 + 0) * DLX + sr] = v.x;
        X[(k2 + 1) * DLX + sr] = v.y;
        X[(k2 + 2) * DLX + sr] = v.z;
        X[(k2 + 3) * DLX + sr] = v.w;
    }
    __syncthreads();   // the ONLY barrier

    const int tx = tid & 31, ty = tid >> 5;   // 16x32 thread grid, 4x2 micro
    float acc[4][2] = {};
    #pragma unroll 4
    for (int k2 = 0; k2 < 128; k2++) {
        uint4 av = *(const uint4*)&X[k2 * DLX + ty * 4];        // 4 i-rows (broadcast x32)
        uint2 bv = *(const uint2*)&X[k2 * DLX + 64 + tx * 2];   // 2 j-rows (2-way banks)
        h2 wv = __builtin_bit_cast(h2, WkS[k2]);
        h2 ai[4] = {__builtin_bit_cast(h2, av.x), __builtin_bit_cast(h2, av.y),
                    __builtin_bit_cast(h2, av.z), __builtin_bit_cast(h2, av.w)};
        h2 bj[2] = {__builtin_bit_cast(h2, bv.x), __builtin_bit_cast(h2, bv.y)};
        #pragma unroll
        for (int ii = 0; ii < 4; ii++)
            #pragma unroll
            for (int jj = 0; jj < 2; jj++) {
                h2 d = habs2(ai[ii] - bj[jj]);
                acc[ii][jj] = FDOT2(d, wv, acc[ii][jj]);
            }
    }

    const int bn = load_boxnum(box_num, b);
    float m[4][2];
    #pragma unroll
    for (int ii = 0; ii < 4; ii++) {
        int i = i0 + ty * 4 + ii;
        bool vi = i < bn;
        #pragma unroll
        for (int jj = 0; jj < 2; jj++) {
            int j = j0 + tx * 2 + jj;
            float v = acc[ii][jj];
            if (!(vi && (j < bn))) v -= sumw;
            m[ii][jj] = v > 0.f ? v : 0.01f * v;
        }
    }
    // primary tile: rows i, cols j (coalesced float2)
    #pragma unroll
    for (int ii = 0; ii < 4; ii++) {
        int i = i0 + ty * 4 + ii;
        float2 o = {m[ii][0], m[ii][1]};
        *(float2*)&dist[((size_t)b * N_ + i) * N_ + j0 + tx * 2] = o;
    }
    // mirror tile: rows j, cols i (diagonal tiles double-write identical bits - benign)
    #pragma unroll
    for (int jj = 0; jj < 2; jj++) {
        int j = j0 + tx * 2 + jj;
        float4 o = {m[0][jj], m[1][jj], m[2][jj], m[3][jj]};
        *(float4*)&dist[((size_t)b * N_ + j) * N_ + i0 + ty * 4] = o;
    }
}

// ---------------- row softmax: 4 waves per block, one row per wave ----------------
__global__ __launch_bounds__(256) void softmax_kernel(float* __restrict__ sa,
                                                      const float* __restrict__ adj) {
    const int row = blockIdx.x * 4 + (threadIdx.x >> 6);
    const int t = threadIdx.x & 63;
    float* prow = sa + (size_t)row * N_;
    const float* arow = adj + (size_t)row * N_;
    float v[6];
    float m = -1e30f;
    #pragma unroll
    for (int qq = 0; qq < 6; qq++) { v[qq] = prow[t + qq * 64]; m = fmaxf(m, v[qq]); }
    #pragma unroll
    for (int off = 32; off > 0; off >>= 1) m = fmaxf(m, __shfl_xor(m, off));
    float e[6];
    float s = 0.f;
    #pragma unroll
    for (int qq = 0; qq < 6; qq++) { e[qq] = arow[t + qq * 64] * expf(v[qq] - m); s += e[qq]; }
    #pragma unroll
    for (int off = 32; off > 0; off >>= 1) s += __shfl_xor(s, off);
    float inv = 1.0f / s;
    #pragma unroll
    for (int qq = 0; qq < 6; qq++) prow[t + qq * 64] = e[qq] * inv + 1e-10f;
}

extern "C" void kernel_launch(void* const* d_in, const int* in_sizes, int n_in,
                              void* d_out, int out_size, void* d_ws, size_t ws_size,
                              hipStream_t stream) {
    const float* x       = (const float*)d_in[0];
    const float* adj     = (const float*)d_in[1];
    const int*   box_num = (const int*)d_in[2];
    const float* fc1_w   = (const float*)d_in[3];
    const float* fc1_b   = (const float*)d_in[4];
    const float* fc2_w   = (const float*)d_in[5];
    const float* fc2_b   = (const float*)d_in[6];
    const float* learn_w = (const float*)d_in[7];

    float* soft_adj = (float*)d_out;
    float* xhat     = (float*)d_out + (size_t)B_ * N_ * N_;

    const int BN = B_ * N_;  // 3072

    // ws layout: [w1h|w1l|w2h|w2l] (bf16, 262144 each) [xh16] (fp16, 786432) [chunk: xh|xl|c1h|c1l]
    bh* w1h = (bh*)d_ws;
    bh* w1l = w1h + (size_t)H_ * D_;
    bh* w2h = w1l + (size_t)H_ * D_;
    bh* w2l = w2h + (size_t)D_ * H_;
    _Float16* xh16 = (_Float16*)(w2l + (size_t)D_ * H_);
    bh* cbase = (bh*)(xh16 + (size_t)BN * D_);
    const size_t fixed_bytes = (size_t)4 * H_ * D_ * 2 + (size_t)BN * D_ * 2;  // 3,670,016
    const size_t per_row = (size_t)(D_ * 2 + H_ * 2) * 2;                       // 5120 B

    long long avail = (long long)ws_size - (long long)fixed_bytes;
    long long mr = (avail > 0) ? (avail / (long long)per_row) : 0;
    if (mr > BN) mr = BN;
    mr &= ~63LL;
    if (mr < 64) mr = 64;   // ws is 256 MiB in this harness; full-size path in practice
    const int max_rows = (int)mr;

    bool first = true;
    for (int m0 = 0; m0 < BN; m0 += max_rows) {
        int rows = BN - m0; if (rows > max_rows) rows = max_rows;
        bh* xh  = cbase;
        bh* xl  = xh + (size_t)max_rows * D_;
        bh* c1h = xl + (size_t)max_rows * D_;
        bh* c1l = c1h + (size_t)max_rows * H_;

        int n0q = rows * D_ / 4;
        int n1q = first ? (H_ * D_ / 4) : 0;
        int n2q = first ? (D_ * H_ / 4) : 0;
        split3_kernel<<<512, 256, 0, stream>>>(
            x + (size_t)m0 * D_, xh, xl, n0q,
            fc1_w, w1h, w1l, n1q,
            fc2_w, w2h, w2l, n2q);

        dim3 g1(H_ / 64, rows / 64);
        gemm1_kernel<<<g1, 256, 0, stream>>>(xh, xl, w1h, w1l, fc1_b, c1h, c1l);
        dim3 g2(D_ / 32, rows / 64);
        gemm2_kernel<<<g2, 256, 0, stream>>>(c1h, c1l, w2h, w2l, fc2_b,
                                             xhat + (size_t)m0 * D_, xh16 + (size_t)m0 * D_);
        first = false;
    }

    dist_kernel<<<B_ * 21, 512, 0, stream>>>(xh16, learn_w, box_num, soft_adj);

    softmax_kernel<<<BN / 4, 256, 0, stream>>>(soft_adj, adj);
}